// Round 1
// 1613.247 us; speedup vs baseline: 1.4285x; 1.4285x over previous
//
#include <hip/hip_runtime.h>
#include <cstddef>
#include <cstdint>

#define B_   2
#define L_   2048
#define C_   768
#define DI   1536   // D_INNER
#define DS   16     // D_STATE
#define DC   4      // D_CONV
#define DTR  48     // DT_RANK
#define E2   3072   // 2*D_INNER
#define NXP  80     // DT_RANK + 2*DS
#define NCH  128    // scan chunks
#define LCH  16     // L per chunk (NCH*LCH == L_)
#define ML   (B_*L_)  // 4096 rows

typedef __bf16 bf16x8 __attribute__((ext_vector_type(8)));
typedef float  f32x4  __attribute__((ext_vector_type(4)));

// ---------------- mean over H*W = 64 ----------------
__global__ __launch_bounds__(256) void k_reduce(const float4* __restrict__ x,
                                                float* __restrict__ xc) {
  int gid = blockIdx.x * 256 + threadIdx.x;
  float4 v = x[gid];
  float s = (v.x + v.y) + (v.z + v.w);
  s += __shfl_xor(s, 1, 16);
  s += __shfl_xor(s, 2, 16);
  s += __shfl_xor(s, 4, 16);
  s += __shfl_xor(s, 8, 16);
  if ((threadIdx.x & 15) == 0) xc[gid >> 4] = s * (1.0f / 64.0f);
}

// ---------------- fp32 -> (hi, lo) bf16 split ----------------
static __device__ __forceinline__ ushort f2bf(float x) {
  uint32_t u = __builtin_bit_cast(uint32_t, x);
  u += 0x7fffu + ((u >> 16) & 1u);          // RNE
  return (ushort)(u >> 16);
}

__global__ __launch_bounds__(256) void k_split(const float4* __restrict__ src,
                                               ushort4* __restrict__ hi,
                                               ushort4* __restrict__ lo) {
  int i = blockIdx.x * 256 + threadIdx.x;
  float4 v = src[i];
  ushort4 h, l;
  h.x = f2bf(v.x); l.x = f2bf(v.x - __builtin_bit_cast(float, (uint32_t)h.x << 16));
  h.y = f2bf(v.y); l.y = f2bf(v.y - __builtin_bit_cast(float, (uint32_t)h.y << 16));
  h.z = f2bf(v.z); l.z = f2bf(v.z - __builtin_bit_cast(float, (uint32_t)h.z << 16));
  h.w = f2bf(v.w); l.w = f2bf(v.w - __builtin_bit_cast(float, (uint32_t)h.w << 16));
  hi[i] = h; lo[i] = l;
}

// ---------------- bf16x2 MFMA GEMM: C = A(MxK) * B(NxK)^T ----------------
// A,B given as hi/lo bf16 planes, row-major [rows][K], K % 32 == 0,
// grid = (M/128, N/128), 256 threads, 4 waves in 2x2 of 64x64.
// acc += Ah*Bh + Ah*Bl + Al*Bh  (fp32 MFMA accumulators).
static __device__ __forceinline__ void gl16(const ushort* g, ushort* l) {
  __builtin_amdgcn_global_load_lds(
      (const __attribute__((address_space(1))) uint32_t*)g,
      (__attribute__((address_space(3))) uint32_t*)l, 16, 0, 0);
}

__global__ __launch_bounds__(256) void k_gemm_mfma(
    const ushort* __restrict__ Ah, const ushort* __restrict__ Al,
    const ushort* __restrict__ Bh, const ushort* __restrict__ Bl,
    float* __restrict__ C, int N, int K) {
  // LDS: 4 planes (Ah,Al,Bh,Bl), each k-slot-major [4 kslots][128 rows][8 bf16]
  // = 4096 ushorts (8KB) per plane. Frag reads: lane granule index = row mod 8
  // -> 2 granules/bank-slot -> conflict-free ds_read_b128.
  __shared__ ushort lds[4 * 4096];
  const int tid  = threadIdx.x;
  const int lane = tid & 63;
  const int wid  = tid >> 6;
  const int wr = wid >> 1, wc = wid & 1;
  const int m0 = blockIdx.x * 128, n0 = blockIdx.y * 128;

  f32x4 acc[4][4];
#pragma unroll
  for (int i = 0; i < 4; ++i)
#pragma unroll
    for (int j = 0; j < 4; ++j) acc[i][j] = (f32x4){0.f, 0.f, 0.f, 0.f};

  // staging: thread n of issue t fetches global (row = n&127, kslot = t*2 + (n>>7))
  const int srow  = tid & 127;
  const int shalf = tid >> 7;
  const size_t rowA = (size_t)(m0 + srow) * K;
  const size_t rowB = (size_t)(n0 + srow) * K;

  // fragment read offsets (ushort units): plane*4096 + q*1024 + row*8
  const int q = lane >> 4, r = lane & 15;
  const int fragA = q * 1024 + (wr * 64 + r) * 8;   // + i*128 for m-frag i
  const int fragB = q * 1024 + (wc * 64 + r) * 8;   // + j*128 for n-frag j

  for (int k0 = 0; k0 < K; k0 += 32) {
    __syncthreads();                     // previous iter's frag reads done
#pragma unroll
    for (int t = 0; t < 2; ++t) {
      const int ko = k0 + (t * 2 + shalf) * 8;
      gl16(Ah + rowA + ko, &lds[0 * 4096 + t * 2048 + tid * 8]);
      gl16(Al + rowA + ko, &lds[1 * 4096 + t * 2048 + tid * 8]);
      gl16(Bh + rowB + ko, &lds[2 * 4096 + t * 2048 + tid * 8]);
      gl16(Bl + rowB + ko, &lds[3 * 4096 + t * 2048 + tid * 8]);
    }
    __syncthreads();                     // drains vmcnt -> tiles resident

    bf16x8 ah[4], al[4], bh[4], bl[4];
#pragma unroll
    for (int i = 0; i < 4; ++i) {
      ah[i] = *(const bf16x8*)&lds[0 * 4096 + fragA + i * 128];
      al[i] = *(const bf16x8*)&lds[1 * 4096 + fragA + i * 128];
      bh[i] = *(const bf16x8*)&lds[2 * 4096 + fragB + i * 128];
      bl[i] = *(const bf16x8*)&lds[3 * 4096 + fragB + i * 128];
    }
#pragma unroll
    for (int i = 0; i < 4; ++i)
#pragma unroll
      for (int j = 0; j < 4; ++j)
        acc[i][j] = __builtin_amdgcn_mfma_f32_16x16x32_bf16(ah[i], bh[j], acc[i][j], 0, 0, 0);
#pragma unroll
    for (int i = 0; i < 4; ++i)
#pragma unroll
      for (int j = 0; j < 4; ++j)
        acc[i][j] = __builtin_amdgcn_mfma_f32_16x16x32_bf16(ah[i], bl[j], acc[i][j], 0, 0, 0);
#pragma unroll
    for (int i = 0; i < 4; ++i)
#pragma unroll
      for (int j = 0; j < 4; ++j)
        acc[i][j] = __builtin_amdgcn_mfma_f32_16x16x32_bf16(al[i], bh[j], acc[i][j], 0, 0, 0);
  }

  // epilogue: D mapping col = lane&15, row = (lane>>4)*4 + reg  (m89-verified)
  const int orow = m0 + wr * 64 + q * 4;
  const int ocol = n0 + wc * 64 + r;
#pragma unroll
  for (int i = 0; i < 4; ++i)
#pragma unroll
    for (int j = 0; j < 4; ++j) {
      float* cp = C + (size_t)(orow + i * 16) * N + (ocol + j * 16);
#pragma unroll
      for (int t = 0; t < 4; ++t) cp[(size_t)t * N] = acc[i][j][t];
    }
}

// ---------------- generic fp32 GEMM (kept for small/awkward shapes) ----------------
// MODE 0: plain store. MODE 1: softplus(acc + bias[n]).
template <int BM, int BN, int TM, int TN, int MODE>
__global__ __launch_bounds__(256) void k_gemm(const float* __restrict__ A, int lda,
                                              const float* __restrict__ Bm, int ldb,
                                              float* __restrict__ Cm, int ldc,
                                              int M, int N, int K,
                                              const float* __restrict__ bias) {
  constexpr int BK = 16;
  __shared__ float As[BK][BM + 4];
  __shared__ float Bs[BK][BN + 4];
  const int tid = threadIdx.x;
  const int tx = tid & 15;
  const int ty = tid >> 4;
  const int m0 = blockIdx.x * BM;
  const int n0 = blockIdx.y * BN;

  float acc[TM][TN];
#pragma unroll
  for (int i = 0; i < TM; ++i)
#pragma unroll
    for (int j = 0; j < TN; ++j) acc[i][j] = 0.f;

  for (int k0 = 0; k0 < K; k0 += BK) {
#pragma unroll
    for (int t = 0; t < BM / 16; ++t) {
      int e = t * 256 + tid;
      int row = e >> 4, col = e & 15;
      int gm = m0 + row, gk = k0 + col;
      As[col][row] = (gm < M && gk < K) ? A[(size_t)gm * lda + gk] : 0.f;
    }
#pragma unroll
    for (int t = 0; t < BN / 16; ++t) {
      int e = t * 256 + tid;
      int row = e >> 4, col = e & 15;
      int gn = n0 + row, gk = k0 + col;
      Bs[col][row] = (gn < N && gk < K) ? Bm[(size_t)gn * ldb + gk] : 0.f;
    }
    __syncthreads();
#pragma unroll
    for (int kk = 0; kk < BK; ++kk) {
      float a[TM], bv[TN];
#pragma unroll
      for (int i = 0; i < TM; ++i) a[i] = As[kk][ty * TM + i];
#pragma unroll
      for (int j = 0; j < TN; ++j) bv[j] = Bs[kk][tx * TN + j];
#pragma unroll
      for (int i = 0; i < TM; ++i)
#pragma unroll
        for (int j = 0; j < TN; ++j) acc[i][j] = fmaf(a[i], bv[j], acc[i][j]);
    }
    __syncthreads();
  }
#pragma unroll
  for (int i = 0; i < TM; ++i) {
    int gm = m0 + ty * TM + i;
    if (gm >= M) continue;
#pragma unroll
    for (int j = 0; j < TN; ++j) {
      int gn = n0 + tx * TN + j;
      if (gn >= N) continue;
      float v = acc[i][j];
      if (MODE == 1) {
        v += bias[gn];
        v = fmaxf(v, 0.f) + log1pf(expf(-fabsf(v)));  // stable softplus
      }
      Cm[(size_t)gm * ldc + gn] = v;
    }
  }
}

// ---------------- causal depthwise conv (4 taps) + SiLU ----------------
__global__ __launch_bounds__(256) void k_conv(const float* __restrict__ xz,
                                              const float* __restrict__ cw,
                                              const float* __restrict__ cb,
                                              float* __restrict__ xh) {
  int gid = blockIdx.x * 256 + threadIdx.x;
  int d = gid % DI;
  int bl = gid / DI;
  int l = bl % L_;
  const float* base = xz + (size_t)(bl - l) * E2 + d;
  float acc = cb[d];
#pragma unroll
  for (int k = 0; k < DC; ++k) {
    int ll = l + k - (DC - 1);
    float xv = (ll >= 0) ? base[(size_t)ll * E2] : 0.f;
    acc = fmaf(xv, cw[d * DC + k], acc);
  }
  float sig = 1.f / (1.f + expf(-acc));
  xh[gid] = acc * sig;
}

// ---------------- scan pass1 ----------------
__global__ __launch_bounds__(256) void k_scan1(const float* __restrict__ delta,
                                               const float* __restrict__ xh,
                                               const float* __restrict__ xdb,
                                               const float* __restrict__ A_log,
                                               float* __restrict__ hend,
                                               float* __restrict__ sd) {
  int tid = threadIdx.x;
  int bid = blockIdx.x;
  int dblk = bid % (DI / 256);
  int c = (bid / (DI / 256)) % NCH;
  int b = bid / ((DI / 256) * NCH);
  int d = dblk * 256 + tid;

  float a[DS];
#pragma unroll
  for (int s = 0; s < DS; ++s) a[s] = -expf(A_log[d * DS + s]);
  float h[DS];
#pragma unroll
  for (int s = 0; s < DS; ++s) h[s] = 0.f;
  float sum_delta = 0.f;

  int l0 = c * LCH;
  for (int i = 0; i < LCH; ++i) {
    size_t bl = (size_t)b * L_ + (l0 + i);
    float dt = delta[bl * DI + d];
    float xv = xh[bl * DI + d];
    sum_delta += dt;
    float u = dt * xv;
    const float* Brow = xdb + bl * NXP + DTR;
#pragma unroll
    for (int s = 0; s < DS; ++s) {
      float dA = expf(dt * a[s]);
      h[s] = fmaf(dA, h[s], u * Brow[s]);
    }
  }
  size_t base = (size_t)(b * NCH + c) * DS * DI;
#pragma unroll
  for (int s = 0; s < DS; ++s) hend[base + (size_t)s * DI + d] = h[s];
  sd[(size_t)(b * NCH + c) * DI + d] = sum_delta;
}

// ---------------- scan pass2 ----------------
__global__ __launch_bounds__(256) void k_scan2(const float* __restrict__ A_log,
                                               const float* __restrict__ sd,
                                               const float* __restrict__ hend,
                                               float* __restrict__ hinit) {
  int gid = blockIdx.x * 256 + threadIdx.x;
  int d = gid % DI;
  int s = (gid / DI) % DS;
  int b = gid / (DI * DS);
  float a = -expf(A_log[d * DS + s]);
  float h = 0.f;
  for (int c = 0; c < NCH; ++c) {
    size_t cb = (size_t)(b * NCH + c);
    size_t hidx = (cb * DS + s) * DI + d;
    hinit[hidx] = h;
    h = fmaf(expf(a * sd[cb * DI + d]), h, hend[hidx]);
  }
}

// ---------------- scan pass3 ----------------
__global__ __launch_bounds__(256) void k_scan3(const float* __restrict__ delta,
                                               float* __restrict__ xh,  // in-out
                                               const float* __restrict__ xdb,
                                               const float* __restrict__ xz,
                                               const float* __restrict__ A_log,
                                               const float* __restrict__ hinit,
                                               const float* __restrict__ Dp) {
  int tid = threadIdx.x;
  int bid = blockIdx.x;
  int dblk = bid % (DI / 256);
  int c = (bid / (DI / 256)) % NCH;
  int b = bid / ((DI / 256) * NCH);
  int d = dblk * 256 + tid;

  float a[DS];
#pragma unroll
  for (int s = 0; s < DS; ++s) a[s] = -expf(A_log[d * DS + s]);
  float h[DS];
  size_t hbase = (size_t)(b * NCH + c) * DS * DI;
#pragma unroll
  for (int s = 0; s < DS; ++s) h[s] = hinit[hbase + (size_t)s * DI + d];
  float dpar = Dp[d];

  int l0 = c * LCH;
  for (int i = 0; i < LCH; ++i) {
    size_t bl = (size_t)b * L_ + (l0 + i);
    float dt = delta[bl * DI + d];
    float xv = xh[bl * DI + d];
    float u = dt * xv;
    const float* row = xdb + bl * NXP;
    float y = 0.f;
#pragma unroll
    for (int s = 0; s < DS; ++s) {
      float dA = expf(dt * a[s]);
      h[s] = fmaf(dA, h[s], u * row[DTR + s]);
      y = fmaf(h[s], row[DTR + DS + s], y);
    }
    float z = xz[bl * E2 + DI + d];
    float sig = 1.f / (1.f + expf(-z));
    xh[bl * DI + d] = (y + xv * dpar) * (z * sig);
  }
}

extern "C" void kernel_launch(void* const* d_in, const int* in_sizes, int n_in,
                              void* d_out, int out_size, void* d_ws, size_t ws_size,
                              hipStream_t stream) {
  const float* x      = (const float*)d_in[0];
  const float* W_in   = (const float*)d_in[1];
  const float* conv_w = (const float*)d_in[2];
  const float* conv_b = (const float*)d_in[3];
  const float* W_xproj= (const float*)d_in[4];
  const float* W_dt   = (const float*)d_in[5];
  const float* b_dt   = (const float*)d_in[6];
  const float* A_log  = (const float*)d_in[7];
  const float* D_param= (const float*)d_in[8];
  const float* W_out  = (const float*)d_in[9];
  float* out = (float*)d_out;
  float* ws = (float*)d_ws;

  // workspace layout (floats)
  float* XC    = ws;                  // 4096*768      = 3,145,728
  float* XZ    = XC    + 3145728;     // 4096*3072     = 12,582,912
  float* XH    = XZ    + 12582912;    // 4096*1536     = 6,291,456
  float* XDB   = XH    + 6291456;     // 4096*80       = 327,680
  float* DELTA = XDB   + 327680;      // 4096*1536     = 6,291,456
  float* SD    = DELTA + 6291456;     // 2*128*1536    = 393,216
  float* HEND  = SD    + 393216;      // 2*128*16*1536 = 6,291,456
  float* HINIT = HEND  + 6291456;     // 6,291,456

  // bf16 split planes in DEAD regions (no extra workspace):
  // phase A (before scan): planes for GEMM2 live inside HEND (first written by scan1)
  ushort* XCh = (ushort*)HEND;            // 3,145,728 ush
  ushort* XCl = XCh + 3145728;            // 3,145,728 ush
  ushort* Wih = XCl + 3145728;            // 2,359,296 ush
  ushort* Wil = Wih + 2359296;            //   (total 11.0M ush < 12.58M of HEND)
  // phase B (after scan3): planes for GEMM9 live in DELTA+SD+HEND (all dead)
  ushort* XHh = (ushort*)DELTA;           // 6,291,456 ush
  ushort* XHl = XHh + 6291456;            // 6,291,456 ush  (fills DELTA exactly)
  ushort* Woh = XHl + 6291456;            // 1,179,648 ush  (into SD/HEND)
  ushort* Wol = Woh + 1179648;

  // 1) xc = mean(x, HW)
  k_reduce<<<(B_*L_*C_*16)/256, 256, 0, stream>>>((const float4*)x, XC);
  // 2) xz = xc @ W_in^T via bf16x2 MFMA  (4096 x 3072, K=768)
  k_split<<<3145728/1024, 256, 0, stream>>>((const float4*)XC,   (ushort4*)XCh, (ushort4*)XCl);
  k_split<<<2359296/1024, 256, 0, stream>>>((const float4*)W_in, (ushort4*)Wih, (ushort4*)Wil);
  k_gemm_mfma<<<dim3(ML/128, E2/128), 256, 0, stream>>>(XCh, XCl, Wih, Wil, XZ, E2, C_);
  // 3) xh = silu(causal_conv(xz[:, :DI]))
  k_conv<<<(B_*L_*DI)/256, 256, 0, stream>>>(XZ, conv_w, conv_b, XH);
  // 4) xdb = xh @ W_xproj^T  (4096 x 80, K=1536)
  k_gemm<64,64,4,4,0><<<dim3(ML/64, 2), 256, 0, stream>>>(
      XH, DI, W_xproj, DI, XDB, NXP, ML, NXP, DI, nullptr);
  // 5) delta = softplus(xdb[:, :48] @ W_dt^T + b_dt)  (4096 x 1536, K=48)
  k_gemm<64,64,4,4,1><<<dim3(ML/64, DI/64), 256, 0, stream>>>(
      XDB, NXP, W_dt, DTR, DELTA, DI, ML, DI, DTR, b_dt);
  // 6-8) chunked selective scan + fused output gating (y written over XH)
  k_scan1<<<B_*NCH*(DI/256), 256, 0, stream>>>(DELTA, XH, XDB, A_log, HEND, SD);
  k_scan2<<<(B_*DS*DI)/256, 256, 0, stream>>>(A_log, SD, HEND, HINIT);
  k_scan3<<<B_*NCH*(DI/256), 256, 0, stream>>>(DELTA, XH, XDB, XZ, A_log, HINIT, D_param);
  // 9) out = y @ W_out^T via bf16x2 MFMA  (4096 x 768, K=1536)
  k_split<<<6291456/1024, 256, 0, stream>>>((const float4*)XH,    (ushort4*)XHh, (ushort4*)XHl);
  k_split<<<1179648/1024, 256, 0, stream>>>((const float4*)W_out, (ushort4*)Woh, (ushort4*)Wol);
  k_gemm_mfma<<<dim3(ML/128, C_/128), 256, 0, stream>>>(XHh, XHl, Woh, Wol, out, C_, DI);
}

// Round 3
// 1570.519 us; speedup vs baseline: 1.4674x; 1.0272x over previous
//
#include <hip/hip_runtime.h>
#include <cstddef>
#include <cstdint>

#define B_   2
#define L_   2048
#define C_   768
#define DI   1536   // D_INNER
#define DS   16     // D_STATE
#define DC   4      // D_CONV
#define DTR  48     // DT_RANK
#define E2   3072   // 2*D_INNER
#define NXP  80     // DT_RANK + 2*DS
#define NCH  128    // scan chunks
#define LCH  16     // L per chunk (NCH*LCH == L_)
#define ML   (B_*L_)  // 4096 rows
#define GSB  2048     // grid-stride block count for streaming kernels

typedef __bf16 bf16x8 __attribute__((ext_vector_type(8)));
typedef float  f32x4  __attribute__((ext_vector_type(4)));

// ---------------- fp32 -> (hi, lo) bf16 split helpers ----------------
static __device__ __forceinline__ ushort f2bf(float x) {
  uint32_t u = __builtin_bit_cast(uint32_t, x);
  u += 0x7fffu + ((u >> 16) & 1u);          // RNE
  return (ushort)(u >> 16);
}
static __device__ __forceinline__ float bf2f(ushort h) {
  return __builtin_bit_cast(float, (uint32_t)h << 16);
}

// ---------------- mean over H*W = 64, fused bf16 hi/lo split ----------------
// grid-stride, 2048 blocks; 16 threads = one (b,l,c) group per pass
__global__ __launch_bounds__(256) void k_reduce(const float4* __restrict__ x,
                                                ushort* __restrict__ hi,
                                                ushort* __restrict__ lo) {
  constexpr int TOT = B_ * L_ * C_ * 16;     // float4 slots
  int tid = threadIdx.x;
#pragma unroll 2
  for (int gid = blockIdx.x * 256 + tid; gid < TOT; gid += GSB * 256) {
    float4 v = x[gid];
    float s = (v.x + v.y) + (v.z + v.w);
    s += __shfl_xor(s, 1, 16);
    s += __shfl_xor(s, 2, 16);
    s += __shfl_xor(s, 4, 16);
    s += __shfl_xor(s, 8, 16);
    if ((tid & 15) == 0) {
      float m = s * (1.0f / 64.0f);
      ushort h = f2bf(m);
      hi[gid >> 4] = h;
      lo[gid >> 4] = f2bf(m - bf2f(h));
    }
  }
}

// ---------------- standalone split (weights only) ----------------
__global__ __launch_bounds__(256) void k_split(const float4* __restrict__ src,
                                               ushort4* __restrict__ hi,
                                               ushort4* __restrict__ lo) {
  int i = blockIdx.x * 256 + threadIdx.x;
  float4 v = src[i];
  ushort4 h, l;
  h.x = f2bf(v.x); l.x = f2bf(v.x - bf2f(h.x));
  h.y = f2bf(v.y); l.y = f2bf(v.y - bf2f(h.y));
  h.z = f2bf(v.z); l.z = f2bf(v.z - bf2f(h.z));
  h.w = f2bf(v.w); l.w = f2bf(v.w - bf2f(h.w));
  hi[i] = h; lo[i] = l;
}

// ---------------- bf16x2 MFMA GEMM: C = A(MxK) * B(NxK)^T ----------------
// A,B as hi/lo bf16 planes, row-major [rows][K], K % 32 == 0.
// grid = (M/128, N/128), 256 threads, 4 waves in 2x2 of 64x64.
// acc += Ah*Bh + Ah*Bl + Al*Bh  (fp32 MFMA accumulators).
// 2-phase pipeline: stage tile t+1 is in flight during tile t's MFMAs;
// single barrier (with its vmcnt/lgkm drain) per K-step.
static __device__ __forceinline__ void gl16(const ushort* g, ushort* l) {
  __builtin_amdgcn_global_load_lds(
      (const __attribute__((address_space(1))) uint32_t*)g,
      (__attribute__((address_space(3))) uint32_t*)l, 16, 0, 0);
}

__global__ __launch_bounds__(256) void k_gemm_mfma(
    const ushort* __restrict__ Ah, const ushort* __restrict__ Al,
    const ushort* __restrict__ Bh, const ushort* __restrict__ Bl,
    float* __restrict__ C, int N, int K) {
  // 2 buffers x 4 planes x [4 kslots][128 rows][8 bf16] (8KB/plane) = 64KB
  __shared__ ushort lds[2][4 * 4096];
  const int tid  = threadIdx.x;
  const int lane = tid & 63;
  const int wid  = tid >> 6;
  const int wr = wid >> 1, wc = wid & 1;
  const int m0 = blockIdx.x * 128, n0 = blockIdx.y * 128;

  f32x4 acc[4][4];
#pragma unroll
  for (int i = 0; i < 4; ++i)
#pragma unroll
    for (int j = 0; j < 4; ++j) acc[i][j] = (f32x4){0.f, 0.f, 0.f, 0.f};

  // staging: thread n of issue t fetches global (row = n&127, kslot = t*2 + (n>>7))
  const int srow  = tid & 127;
  const int shalf = tid >> 7;
  const size_t rowA = (size_t)(m0 + srow) * K;
  const size_t rowB = (size_t)(n0 + srow) * K;

  // fragment read offsets (ushort units): plane*4096 + q*1024 + row*8
  const int q = lane >> 4, r = lane & 15;
  const int fragA = q * 1024 + (wr * 64 + r) * 8;   // + i*128 for m-frag i
  const int fragB = q * 1024 + (wc * 64 + r) * 8;   // + j*128 for n-frag j

  auto STAGE = [&](int buf, int k0) {
    ushort* l = lds[buf];
#pragma unroll
    for (int t = 0; t < 2; ++t) {
      const int ko = k0 + (t * 2 + shalf) * 8;
      gl16(Ah + rowA + ko, &l[0 * 4096 + t * 2048 + tid * 8]);
      gl16(Al + rowA + ko, &l[1 * 4096 + t * 2048 + tid * 8]);
      gl16(Bh + rowB + ko, &l[2 * 4096 + t * 2048 + tid * 8]);
      gl16(Bl + rowB + ko, &l[3 * 4096 + t * 2048 + tid * 8]);
    }
  };

  STAGE(0, 0);
  const int nt = K >> 5;
  int cur = 0;
  for (int t = 0; t < nt; ++t) {
    __syncthreads();                  // buf[cur] staged; prev frag reads drained
    if (t + 1 < nt) STAGE(cur ^ 1, (t + 1) * 32);   // in flight under MFMAs

    const ushort* l = lds[cur];
    bf16x8 ah[4], al[4], bh[4], bl[4];
#pragma unroll
    for (int i = 0; i < 4; ++i) {
      ah[i] = *(const bf16x8*)&l[0 * 4096 + fragA + i * 128];
      al[i] = *(const bf16x8*)&l[1 * 4096 + fragA + i * 128];
      bh[i] = *(const bf16x8*)&l[2 * 4096 + fragB + i * 128];
      bl[i] = *(const bf16x8*)&l[3 * 4096 + fragB + i * 128];
    }
#pragma unroll
    for (int i = 0; i < 4; ++i)
#pragma unroll
      for (int j = 0; j < 4; ++j)
        acc[i][j] = __builtin_amdgcn_mfma_f32_16x16x32_bf16(ah[i], bh[j], acc[i][j], 0, 0, 0);
#pragma unroll
    for (int i = 0; i < 4; ++i)
#pragma unroll
      for (int j = 0; j < 4; ++j)
        acc[i][j] = __builtin_amdgcn_mfma_f32_16x16x32_bf16(ah[i], bl[j], acc[i][j], 0, 0, 0);
#pragma unroll
    for (int i = 0; i < 4; ++i)
#pragma unroll
      for (int j = 0; j < 4; ++j)
        acc[i][j] = __builtin_amdgcn_mfma_f32_16x16x32_bf16(al[i], bh[j], acc[i][j], 0, 0, 0);
    cur ^= 1;
  }

  // epilogue: D mapping col = lane&15, row = (lane>>4)*4 + reg  (m89-verified)
  const int orow = m0 + wr * 64 + q * 4;
  const int ocol = n0 + wc * 64 + r;
#pragma unroll
  for (int i = 0; i < 4; ++i)
#pragma unroll
    for (int j = 0; j < 4; ++j) {
      float* cp = C + (size_t)(orow + i * 16) * N + (ocol + j * 16);
#pragma unroll
      for (int t = 0; t < 4; ++t) cp[(size_t)t * N] = acc[i][j][t];
    }
}

// ---------------- generic fp32 GEMM (small/awkward shapes) ----------------
// MODE 0: plain store. MODE 1: softplus(acc + bias[n]).
template <int BM, int BN, int TM, int TN, int MODE>
__global__ __launch_bounds__(256) void k_gemm(const float* __restrict__ A, int lda,
                                              const float* __restrict__ Bm, int ldb,
                                              float* __restrict__ Cm, int ldc,
                                              int M, int N, int K,
                                              const float* __restrict__ bias) {
  constexpr int BK = 16;
  __shared__ float As[BK][BM + 4];
  __shared__ float Bs[BK][BN + 4];
  const int tid = threadIdx.x;
  const int tx = tid & 15;
  const int ty = tid >> 4;
  const int m0 = blockIdx.x * BM;
  const int n0 = blockIdx.y * BN;

  float acc[TM][TN];
#pragma unroll
  for (int i = 0; i < TM; ++i)
#pragma unroll
    for (int j = 0; j < TN; ++j) acc[i][j] = 0.f;

  for (int k0 = 0; k0 < K; k0 += BK) {
#pragma unroll
    for (int t = 0; t < BM / 16; ++t) {
      int e = t * 256 + tid;
      int row = e >> 4, col = e & 15;
      int gm = m0 + row, gk = k0 + col;
      As[col][row] = (gm < M && gk < K) ? A[(size_t)gm * lda + gk] : 0.f;
    }
#pragma unroll
    for (int t = 0; t < BN / 16; ++t) {
      int e = t * 256 + tid;
      int row = e >> 4, col = e & 15;
      int gn = n0 + row, gk = k0 + col;
      Bs[col][row] = (gn < N && gk < K) ? Bm[(size_t)gn * ldb + gk] : 0.f;
    }
    __syncthreads();
#pragma unroll
    for (int kk = 0; kk < BK; ++kk) {
      float a[TM], bv[TN];
#pragma unroll
      for (int i = 0; i < TM; ++i) a[i] = As[kk][ty * TM + i];
#pragma unroll
      for (int j = 0; j < TN; ++j) bv[j] = Bs[kk][tx * TN + j];
#pragma unroll
      for (int i = 0; i < TM; ++i)
#pragma unroll
        for (int j = 0; j < TN; ++j) acc[i][j] = fmaf(a[i], bv[j], acc[i][j]);
    }
    __syncthreads();
  }
#pragma unroll
  for (int i = 0; i < TM; ++i) {
    int gm = m0 + ty * TM + i;
    if (gm >= M) continue;
#pragma unroll
    for (int j = 0; j < TN; ++j) {
      int gn = n0 + tx * TN + j;
      if (gn >= N) continue;
      float v = acc[i][j];
      if (MODE == 1) {
        v += bias[gn];
        v = fmaxf(v, 0.f) + log1pf(expf(-fabsf(v)));  // stable softplus
      }
      Cm[(size_t)gm * ldc + gn] = v;
    }
  }
}

// ---------------- causal depthwise conv (4 taps) + SiLU, grid-stride ----------------
__global__ __launch_bounds__(256) void k_conv(const float* __restrict__ xz,
                                              const float* __restrict__ cw,
                                              const float* __restrict__ cb,
                                              float* __restrict__ xh) {
  constexpr int TOT = B_ * L_ * DI;
  for (int gid = blockIdx.x * 256 + threadIdx.x; gid < TOT; gid += GSB * 256) {
    int d = gid % DI;
    int bl = gid / DI;
    int l = bl % L_;
    const float* base = xz + (size_t)(bl - l) * E2 + d;
    float acc = cb[d];
#pragma unroll
    for (int k = 0; k < DC; ++k) {
      int ll = l + k - (DC - 1);
      float xv = (ll >= 0) ? base[(size_t)ll * E2] : 0.f;
      acc = fmaf(xv, cw[d * DC + k], acc);
    }
    float sig = 1.f / (1.f + expf(-acc));
    xh[gid] = acc * sig;
  }
}

// ---------------- scan pass1 ----------------
__global__ __launch_bounds__(256) void k_scan1(const float* __restrict__ delta,
                                               const float* __restrict__ xh,
                                               const float* __restrict__ xdb,
                                               const float* __restrict__ A_log,
                                               float* __restrict__ hend,
                                               float* __restrict__ sd) {
  int tid = threadIdx.x;
  int bid = blockIdx.x;
  int dblk = bid % (DI / 256);
  int c = (bid / (DI / 256)) % NCH;
  int b = bid / ((DI / 256) * NCH);
  int d = dblk * 256 + tid;

  float a[DS];
#pragma unroll
  for (int s = 0; s < DS; ++s) a[s] = -expf(A_log[d * DS + s]);
  float h[DS];
#pragma unroll
  for (int s = 0; s < DS; ++s) h[s] = 0.f;
  float sum_delta = 0.f;

  int l0 = c * LCH;
  for (int i = 0; i < LCH; ++i) {
    size_t bl = (size_t)b * L_ + (l0 + i);
    float dt = delta[bl * DI + d];
    float xv = xh[bl * DI + d];
    sum_delta += dt;
    float u = dt * xv;
    const float* Brow = xdb + bl * NXP + DTR;
#pragma unroll
    for (int s = 0; s < DS; ++s) {
      float dA = expf(dt * a[s]);
      h[s] = fmaf(dA, h[s], u * Brow[s]);
    }
  }
  size_t base = (size_t)(b * NCH + c) * DS * DI;
#pragma unroll
  for (int s = 0; s < DS; ++s) hend[base + (size_t)s * DI + d] = h[s];
  sd[(size_t)(b * NCH + c) * DI + d] = sum_delta;
}

// ---------------- scan pass2 ----------------
__global__ __launch_bounds__(256) void k_scan2(const float* __restrict__ A_log,
                                               const float* __restrict__ sd,
                                               const float* __restrict__ hend,
                                               float* __restrict__ hinit) {
  int gid = blockIdx.x * 256 + threadIdx.x;
  int d = gid % DI;
  int s = (gid / DI) % DS;
  int b = gid / (DI * DS);
  float a = -expf(A_log[d * DS + s]);
  float h = 0.f;
  for (int c = 0; c < NCH; ++c) {
    size_t cb = (size_t)(b * NCH + c);
    size_t hidx = (cb * DS + s) * DI + d;
    hinit[hidx] = h;
    h = fmaf(expf(a * sd[cb * DI + d]), h, hend[hidx]);
  }
}

// ---------------- scan pass3: replay + epilogue, fused bf16 hi/lo y output ----------------
__global__ __launch_bounds__(256) void k_scan3(const float* __restrict__ delta,
                                               const float* __restrict__ xh,
                                               const float* __restrict__ xdb,
                                               const float* __restrict__ xz,
                                               const float* __restrict__ A_log,
                                               const float* __restrict__ hinit,
                                               const float* __restrict__ Dp,
                                               ushort* __restrict__ yhi,
                                               ushort* __restrict__ ylo) {
  int tid = threadIdx.x;
  int bid = blockIdx.x;
  int dblk = bid % (DI / 256);
  int c = (bid / (DI / 256)) % NCH;
  int b = bid / ((DI / 256) * NCH);
  int d = dblk * 256 + tid;

  float a[DS];
#pragma unroll
  for (int s = 0; s < DS; ++s) a[s] = -expf(A_log[d * DS + s]);
  float h[DS];
  size_t hbase = (size_t)(b * NCH + c) * DS * DI;
#pragma unroll
  for (int s = 0; s < DS; ++s) h[s] = hinit[hbase + (size_t)s * DI + d];
  float dpar = Dp[d];

  int l0 = c * LCH;
  for (int i = 0; i < LCH; ++i) {
    size_t bl = (size_t)b * L_ + (l0 + i);
    float dt = delta[bl * DI + d];
    float xv = xh[bl * DI + d];
    float u = dt * xv;
    const float* row = xdb + bl * NXP;
    float y = 0.f;
#pragma unroll
    for (int s = 0; s < DS; ++s) {
      float dA = expf(dt * a[s]);
      h[s] = fmaf(dA, h[s], u * row[DTR + s]);
      y = fmaf(h[s], row[DTR + DS + s], y);
    }
    float z = xz[bl * E2 + DI + d];
    float sig = 1.f / (1.f + expf(-z));
    float yv = (y + xv * dpar) * (z * sig);
    ushort hh = f2bf(yv);
    yhi[bl * DI + d] = hh;
    ylo[bl * DI + d] = f2bf(yv - bf2f(hh));
  }
}

extern "C" void kernel_launch(void* const* d_in, const int* in_sizes, int n_in,
                              void* d_out, int out_size, void* d_ws, size_t ws_size,
                              hipStream_t stream) {
  const float* x      = (const float*)d_in[0];
  const float* W_in   = (const float*)d_in[1];
  const float* conv_w = (const float*)d_in[2];
  const float* conv_b = (const float*)d_in[3];
  const float* W_xproj= (const float*)d_in[4];
  const float* W_dt   = (const float*)d_in[5];
  const float* b_dt   = (const float*)d_in[6];
  const float* A_log  = (const float*)d_in[7];
  const float* D_param= (const float*)d_in[8];
  const float* W_out  = (const float*)d_in[9];
  float* out = (float*)d_out;
  float* ws = (float*)d_ws;

  // workspace layout (floats)
  float* XC    = ws;                  // 4096*768      = 3,145,728 (now bf16 plane storage)
  float* XZ    = XC    + 3145728;     // 4096*3072     = 12,582,912
  float* XH    = XZ    + 12582912;    // 4096*1536     = 6,291,456 (conv out, stays fp32)
  float* XDB   = XH    + 6291456;     // 4096*80       = 327,680
  float* DELTA = XDB   + 327680;      // 4096*1536     = 6,291,456
  float* SD    = DELTA + 6291456;     // 2*128*1536    = 393,216
  float* HEND  = SD    + 393216;      // 2*128*16*1536 = 6,291,456
  float* HINIT = HEND  + 6291456;     // 6,291,456

  // bf16 plane aliasing (stream-order verified):
  // phase A: XCh/XCl in XC region (written by k_reduce; dead after GEMM2);
  //          Wih/Wil in HEND (dead until scan1 writes fp32 hend, after GEMM2).
  // phase B: XHh/XHl in HEND (hend fp32 dead after scan2; scan3 writes planes);
  //          Woh/Wol in XC region (XCh dead after GEMM2; split runs after scan3).
  ushort* XCh = (ushort*)XC;              // 3,145,728 ush
  ushort* XCl = XCh + 3145728;            // exact fit in XC region
  ushort* Wih = (ushort*)HEND;            // 2,359,296 ush
  ushort* Wil = Wih + 2359296;
  ushort* XHh = (ushort*)HEND;            // 6,291,456 ush
  ushort* XHl = XHh + 6291456;            // exact fit in HEND region
  ushort* Woh = (ushort*)XC;              // 1,179,648 ush
  ushort* Wol = Woh + 1179648;

  // 1) xc = mean(x, HW), fused bf16 hi/lo emit
  k_reduce<<<GSB, 256, 0, stream>>>((const float4*)x, XCh, XCl);
  // 2) xz = xc @ W_in^T via bf16x2 MFMA  (4096 x 3072, K=768)
  k_split<<<2359296/1024, 256, 0, stream>>>((const float4*)W_in, (ushort4*)Wih, (ushort4*)Wil);
  k_gemm_mfma<<<dim3(ML/128, E2/128), 256, 0, stream>>>(XCh, XCl, Wih, Wil, XZ, E2, C_);
  // 3) xh = silu(causal_conv(xz[:, :DI]))
  k_conv<<<GSB, 256, 0, stream>>>(XZ, conv_w, conv_b, XH);
  // 4) xdb = xh @ W_xproj^T  (4096 x 80, K=1536) — 256 wgs
  k_gemm<32,64,2,4,0><<<dim3(ML/32, 2), 256, 0, stream>>>(
      XH, DI, W_xproj, DI, XDB, NXP, ML, NXP, DI, nullptr);
  // 5) delta = softplus(xdb[:, :48] @ W_dt^T + b_dt)  (4096 x 1536, K=48)
  k_gemm<64,64,4,4,1><<<dim3(ML/64, DI/64), 256, 0, stream>>>(
      XDB, NXP, W_dt, DTR, DELTA, DI, ML, DI, DTR, b_dt);
  // 6-8) chunked selective scan; scan3 emits y as bf16 hi/lo planes
  k_scan1<<<B_*NCH*(DI/256), 256, 0, stream>>>(DELTA, XH, XDB, A_log, HEND, SD);
  k_scan2<<<(B_*DS*DI)/256, 256, 0, stream>>>(A_log, SD, HEND, HINIT);
  k_scan3<<<B_*NCH*(DI/256), 256, 0, stream>>>(DELTA, XH, XDB, XZ, A_log, HINIT,
                                               D_param, XHh, XHl);
  // 9) out = y @ W_out^T via bf16x2 MFMA  (4096 x 768, K=1536)
  k_split<<<1179648/1024, 256, 0, stream>>>((const float4*)W_out, (ushort4*)Woh, (ushort4*)Wol);
  k_gemm_mfma<<<dim3(ML/128, C_/128), 256, 0, stream>>>(XHh, XHl, Woh, Wol, out, C_, DI);
}